// Round 1
// baseline (173.468 us; speedup 1.0000x reference)
//
#include <hip/hip_runtime.h>

// DynamicMaskHead fused v5 (MI355X / gfx950)
// Single dispatch: pack_kernel folded away — mask_feats (2 MB, L2-resident)
// read directly as 8 coalesced channel-plane dwords per pixel (uniform
// SGPR base + shared voffset => no per-load address VALU).
// Tile merged 17x128 -> 33x128 (32 logits rows -> 64 out rows per block):
// halo recompute 6.25% -> 3%, half the blocks, half the per-block
// weight-load prologue. Parity-split LDS kept (conflict-free phase-B reads).
//
// aligned_bilinear(factor=2): odd Y -> copy logits row (Y-1)/2; even Y ->
// avg rows (Y/2-1, Y/2); Y=0 falls out via clamped halo. Same in X:
// out[4l..4l+3] from logits cols {2l-1, 2l, 2l+1}.

#define HW 16384
#define NP 169

__global__ __launch_bounds__(256, 6)
void dmh_kernel(const float* __restrict__ mask_feats,   // (4,8,128,128)
                const float* __restrict__ mask_shift,   // (16384,2)
                const float* __restrict__ shifts,       // (n,2)
                const float* __restrict__ inst_params,  // (n,169)
                const int*   __restrict__ im_inds,      // (n,)
                const int*   __restrict__ fpn_levels,   // (n,)
                float*       __restrict__ out)          // (n,1,256,256)
{
    __shared__ float lgE[33 * 64];   // even cols of 33x128 logits tile
    __shared__ float lgO[33 * 64];   // odd cols

    const int bx   = blockIdx.x;
    const int inst = bx >> 2;
    const int rg   = bx & 3;
    const int tid  = threadIdx.x;
    const int r0   = rg * 32;        // first non-halo logits row of group

    const int img = im_inds[inst];
    const float* __restrict__ wp = inst_params + (size_t)inst * NP;
    const float s0  = shifts[2 * inst];
    const float s1  = shifts[2 * inst + 1];
    const float inv = 1.0f / (float)(64 << fpn_levels[inst]);
    const float* __restrict__ fb = mask_feats + (size_t)img * 8 * HW;

    // ---- phase A: MLP over 33x128 tile (tile px p -> tile row p>>7) ----
    auto load_px = [&](int p, float* x) {
        const int t = p >> 7;                       // 0..32
        const int c = p & 127;
        const int r = min(max(r0 - 1 + t, 0), 127); // clamped halo
        const int g = r * 128 + c;
        const float2 ms = *(const float2*)(mask_shift + 2 * g);
        x[0] = (s0 - ms.x) * inv;
        x[1] = (s1 - ms.y) * inv;
        #pragma unroll
        for (int k = 0; k < 8; ++k) x[2 + k] = fb[k * HW + g];
    };

    auto store_px = [&](int p, float v) {
        const int t = p >> 7;
        const int c = p & 127;
        const int idx = t * 64 + (c >> 1);
        if (c & 1) lgO[idx] = v; else lgE[idx] = v;
    };

    // pair-processing: 8 pair-calls cover 4096 px, tail covers 128
    #pragma unroll 4
    for (int u = 0; u < 8; ++u) {
        const int pA = tid + 512 * u;
        const int pB = pA + 256;
        float xa[10], xb[10];
        load_px(pA, xa);
        load_px(pB, xb);

        float ya[8], yb[8];
        #pragma unroll
        for (int o = 0; o < 8; ++o) {
            const float bia = wp[152 + o];
            float a = bia, b = bia;
            #pragma unroll
            for (int c = 0; c < 10; ++c) {
                const float w = wp[o * 10 + c];
                a = fmaf(w, xa[c], a);
                b = fmaf(w, xb[c], b);
            }
            ya[o] = fmaxf(a, 0.f);
            yb[o] = fmaxf(b, 0.f);
        }
        float za[8], zb[8];
        #pragma unroll
        for (int o = 0; o < 8; ++o) {
            const float bia = wp[160 + o];
            float a = bia, b = bia;
            #pragma unroll
            for (int c = 0; c < 8; ++c) {
                const float w = wp[80 + o * 8 + c];
                a = fmaf(w, ya[c], a);
                b = fmaf(w, yb[c], b);
            }
            za[o] = fmaxf(a, 0.f);
            zb[o] = fmaxf(b, 0.f);
        }
        float va = wp[168], vb = va;
        #pragma unroll
        for (int c = 0; c < 8; ++c) {
            const float w = wp[144 + c];
            va = fmaf(w, za[c], va);
            vb = fmaf(w, zb[c], vb);
        }
        store_px(pA, va);
        store_px(pB, vb);
    }

    if (tid < 128) {                 // tail px 4096..4223 (row t=32)
        const int p = 4096 + tid;
        float x[10];
        load_px(p, x);
        float y1[8];
        #pragma unroll
        for (int o = 0; o < 8; ++o) {
            float a = wp[152 + o];
            #pragma unroll
            for (int c = 0; c < 10; ++c) a = fmaf(wp[o * 10 + c], x[c], a);
            y1[o] = fmaxf(a, 0.f);
        }
        float y2[8];
        #pragma unroll
        for (int o = 0; o < 8; ++o) {
            float a = wp[160 + o];
            #pragma unroll
            for (int c = 0; c < 8; ++c) a = fmaf(wp[80 + o * 8 + c], y1[c], a);
            y2[o] = fmaxf(a, 0.f);
        }
        float v = wp[168];
        #pragma unroll
        for (int c = 0; c < 8; ++c) v = fmaf(wp[144 + c], y2[c], v);
        store_px(p, v);
    }

    __syncthreads();

    // ---- phase B: 64 output rows x 256 cols, float4 stores ----
    float* __restrict__ op =
        out + (size_t)inst * 65536 + (size_t)(2 * r0) * 256;
    const int w = tid >> 6;          // wave 0..3
    const int l = tid & 63;
    const int parity = w & 1;        // wave-uniform row parity

    #pragma unroll
    for (int j = 0; j < 16; ++j) {
        const int p2 = (w >> 1) + 2 * j;     // 0..31
        const int yl = 2 * p2 + parity;      // 0..63
        float4 res;
        if (parity) {                // odd row: copy logits row (tile p2+1)
            const float* e = lgE + (p2 + 1) * 64;
            const float* o = lgO + (p2 + 1) * 64;
            const float v0 = e[l];
            const float v1 = o[l];
            const float vm = (l > 0) ? o[l - 1] : v0;
            res = make_float4(0.5f * (vm + v0), v0, 0.5f * (v0 + v1), v1);
        } else {                     // even row: avg tile rows p2, p2+1
            const float* eA = lgE + p2 * 64;
            const float* oA = lgO + p2 * 64;
            const float* eB = eA + 64;
            const float* oB = oA + 64;
            const float v0A = eA[l], v1A = oA[l];
            const float v0B = eB[l], v1B = oB[l];
            const float vmA = (l > 0) ? oA[l - 1] : v0A;
            const float vmB = (l > 0) ? oB[l - 1] : v0B;
            res = make_float4(0.25f * (vmA + v0A + vmB + v0B),
                              0.5f  * (v0A + v0B),
                              0.25f * (v0A + v1A + v0B + v1B),
                              0.5f  * (v1A + v1B));
        }
        *(float4*)(op + yl * 256 + 4 * l) = res;
    }
}

extern "C" void kernel_launch(void* const* d_in, const int* in_sizes, int n_in,
                              void* d_out, int out_size, void* d_ws, size_t ws_size,
                              hipStream_t stream) {
    (void)n_in; (void)out_size; (void)d_ws; (void)ws_size;
    const float* mask_feats  = (const float*)d_in[0];
    const float* mask_shift  = (const float*)d_in[1];
    const float* shifts      = (const float*)d_in[2];
    const float* inst_params = (const float*)d_in[3];
    const int*   im_inds     = (const int*)d_in[4];
    const int*   fpn_levels  = (const int*)d_in[5];
    float* out = (float*)d_out;

    const int n_inst = in_sizes[2] / 2;            // shifts is (n,2)

    dmh_kernel<<<dim3(n_inst * 4), dim3(256), 0, stream>>>(
        mask_feats, mask_shift, shifts, inst_params, im_inds, fpn_levels,
        out);
}